// Round 1
// baseline (1125.446 us; speedup 1.0000x reference)
//
#include <hip/hip_runtime.h>
#include <stdint.h>

#define NSEG 2048
#define NTOT 1048576
#define CAP  624            // max nodes per segment held in LDS (multiple of 16)
#define BLK  512
#define H_BYTES (CAP * 256)                      // bf16 h[CAP][128]
#define LDS_BYTES (H_BYTES + 4 * (128 + 128 + 512))  // + colsum + lbias + wbuf

typedef __bf16 bf16x8 __attribute__((ext_vector_type(8)));
typedef float  f32x4  __attribute__((ext_vector_type(4)));
typedef unsigned short u16x8 __attribute__((ext_vector_type(8)));

__device__ __forceinline__ unsigned short f2bf(float f) {
    uint32_t u = __float_as_uint(f);
    u += 0x7FFFu + ((u >> 16) & 1u);           // round-to-nearest-even
    return (unsigned short)(u >> 16);
}
__device__ __forceinline__ float bf2f(unsigned short h) {
    return __uint_as_float(((uint32_t)h) << 16);
}
// swizzled byte address into LDS h tile: row pitch 256B, XOR bits 4-6 by row&7
__device__ __forceinline__ uint32_t haddr(int row, int bytecol) {
    return ((uint32_t)row * 256u + (uint32_t)bytecol) ^ (((uint32_t)row & 7u) << 4);
}
__device__ __forceinline__ float leaky(float v) {
    return fmaxf(v, 0.f) + 0.01f * fminf(v, 0.f);
}

// offs[t] = lower_bound(seg, t): segment t occupies [offs[t], offs[t+1])
__global__ void seg_offsets_kernel(const int* __restrict__ seg, int* __restrict__ offs) {
    int t = blockIdx.x * blockDim.x + threadIdx.x;
    if (t > NSEG) return;
    int lo = 0, hi = NTOT;
    while (lo < hi) { int mid = (lo + hi) >> 1; if (seg[mid] < t) lo = mid + 1; else hi = mid; }
    offs[t] = lo;
}

// Wt[m][n][k] = bf16(W_m[k][n])  (transposed so k is contiguous for fragment loads)
__global__ void wconv_kernel(const float* __restrict__ W1b, const float* __restrict__ W2,
                             const float* __restrict__ W3,  const float* __restrict__ W4,
                             const float* __restrict__ W5,  unsigned short* __restrict__ wt) {
    int idx = blockIdx.x * blockDim.x + threadIdx.x;   // 0 .. 5*16384-1
    int m = idx >> 14, e = idx & 16383;
    int nn = e >> 7, kk = e & 127;
    const float* W = (m == 0) ? W1b : (m == 1) ? W2 : (m == 2) ? W3 : (m == 3) ? W4 : W5;
    wt[idx] = f2bf(W[kk * 128 + nn]);
}

extern __shared__ char smem[];

__global__ __launch_bounds__(BLK, 2) void fused_pflow(
    const float* __restrict__ feat, const int* __restrict__ offs,
    const unsigned short* __restrict__ wt5,
    const float* __restrict__ W1a, const float* __restrict__ b1a,
    const float* __restrict__ b1b, const float* __restrict__ b2,
    const float* __restrict__ b3,  const float* __restrict__ b4,
    const float* __restrict__ b5,
    const float* __restrict__ Wo1, const float* __restrict__ bo1,
    const float* __restrict__ Wo2, const float* __restrict__ bo2,
    float* __restrict__ out)
{
    const int s    = blockIdx.x;
    const int tid  = threadIdx.x;
    const int lane = tid & 63;
    const int wave = tid >> 6;
    const int lm   = lane & 15;    // MFMA "column" lane (node / A-row)
    const int lq   = lane >> 4;    // k-quad / C row-quad

    char*  sm     = smem;
    float* colsum = (float*)(sm + H_BYTES);
    float* lbias  = colsum + 128;
    float* wbuf   = lbias + 128;   // 512 floats: W1a (384) + b1a (128)

    const int g0 = offs[s];
    int n = offs[s + 1] - g0;
    n = n < CAP ? n : CAP;

    for (int i = tid; i < 512; i += BLK) wbuf[i] = (i < 384) ? W1a[i] : b1a[i - 384];
    if (tid < 128) colsum[tid] = 0.f;
    __syncthreads();

    // ---- layer 1a: h = leaky(feat @ W1a + b1a), fp32 VALU (K=3) ----
    for (int i = tid; i < n; i += BLK) {
        float f0 = feat[(g0 + i) * 3 + 0];
        float f1 = feat[(g0 + i) * 3 + 1];
        float f2 = feat[(g0 + i) * 3 + 2];
        #pragma unroll
        for (int c = 0; c < 128; c += 2) {
            float v0 = leaky(fmaf(f0, wbuf[c],     fmaf(f1, wbuf[128 + c],     fmaf(f2, wbuf[256 + c],     wbuf[384 + c]))));
            float v1 = leaky(fmaf(f0, wbuf[c + 1], fmaf(f1, wbuf[128 + c + 1], fmaf(f2, wbuf[256 + c + 1], wbuf[384 + c + 1]))));
            uint32_t p = (uint32_t)f2bf(v0) | ((uint32_t)f2bf(v1) << 16);
            *(uint32_t*)(sm + haddr(i, c * 2)) = p;
        }
    }

    const int   ntiles = (n + 15) >> 4;
    const float inv_n  = 1.f / (float)(n > 1 ? n : 1);

    // ---- 5 GEMM layers: h = leaky(h @ W + b); residual += mean for L<4 ----
    for (int L = 0; L < 5; ++L) {
        const unsigned short* wt = wt5 + L * 16384;
        const float* bias = (L == 0) ? b1b : (L == 1) ? b2 : (L == 2) ? b3 : (L == 3) ? b4 : b5;
        if (tid < 128) lbias[tid] = bias[tid];
        __syncthreads();                                     // B1: h stable, lbias/colsum ready

        // A = W^T fragments, whole 128x128 W register-resident (128 VGPR)
        bf16x8 afrag[8][4];
        #pragma unroll
        for (int ct = 0; ct < 8; ++ct)
            #pragma unroll
            for (int ks = 0; ks < 4; ++ks)
                afrag[ct][ks] = *(const bf16x8*)(wt + (ct * 16 + lm) * 128 + ks * 32 + lq * 8);

        float creg[8][4] = {};   // per-lane column-sum partials, ch = ct*16 + lq*4 + i

        for (int rt = wave; rt < ntiles; rt += 8) {
            const int node = rt * 16 + lm;
            bf16x8 bfrag[4];     // B = h^T: 8 contiguous features of this lane's node
            #pragma unroll
            for (int ks = 0; ks < 4; ++ks)
                bfrag[ks] = *(const bf16x8*)(sm + haddr(node, ks * 64 + lq * 16));
            f32x4 acc[8] = {};
            #pragma unroll
            for (int ks = 0; ks < 4; ++ks)
                #pragma unroll
                for (int ct = 0; ct < 8; ++ct)
                    acc[ct] = __builtin_amdgcn_mfma_f32_16x16x32_bf16(afrag[ct][ks], bfrag[ks], acc[ct], 0, 0, 0);
            const bool valid = node < n;
            #pragma unroll
            for (int ct = 0; ct < 8; ++ct) {
                uint64_t pk = 0;
                #pragma unroll
                for (int i = 0; i < 4; ++i) {
                    const int ch = ct * 16 + lq * 4 + i;
                    float v = leaky(acc[ct][i] + lbias[ch]);
                    if (valid) creg[ct][i] += v;
                    pk |= ((uint64_t)f2bf(v)) << (16 * i);
                }
                if (valid) *(uint64_t*)(sm + haddr(node, (ct * 16 + lq * 4) * 2)) = pk;  // 4 ch of one node
            }
        }
        // reduce column-sum partials over the 16 node-lanes, then one atomic per channel
        #pragma unroll
        for (int ct = 0; ct < 8; ++ct)
            #pragma unroll
            for (int i = 0; i < 4; ++i) {
                float v = creg[ct][i];
                v += __shfl_xor(v, 1); v += __shfl_xor(v, 2);
                v += __shfl_xor(v, 4); v += __shfl_xor(v, 8);
                if (lm == 0) atomicAdd(&colsum[ct * 16 + lq * 4 + i], v);
            }
        __syncthreads();                                     // B2: writes + atomics done
        if (tid < 128) colsum[tid] *= inv_n;                 // colsum -> mean
        __syncthreads();                                     // B3: mean ready
        if (L < 4) {
            const int tot = n * 16;                          // 16x 16B chunks per row
            for (int idx = tid; idx < tot; idx += BLK) {
                const int row = idx >> 4, c0 = (idx & 15) * 8;
                char* p = sm + haddr(row, c0 * 2);
                u16x8 hv = *(u16x8*)p, ov;
                #pragma unroll
                for (int j = 0; j < 8; ++j) ov[j] = f2bf(bf2f(hv[j]) + colsum[c0 + j]);
                *(u16x8*)p = ov;
            }
            __syncthreads();                                 // B4: sweep done
            if (tid < 128) colsum[tid] = 0.f;                // next B1 orders this vs atomics
        }
    }

    // ---- output head: colsum holds g[128]; e = leaky(g@Wo1+bo1)@Wo2 + bo2 ----
    if (wave == 0) {
        float a = bo1[lane];                                 // 64 lanes = 64 hidden units
        for (int k = 0; k < 128; ++k) a = fmaf(colsum[k], Wo1[k * 64 + lane], a);
        a = leaky(a);
        float e = a * Wo2[lane];
        e += __shfl_xor(e, 32); e += __shfl_xor(e, 16); e += __shfl_xor(e, 8);
        e += __shfl_xor(e, 4);  e += __shfl_xor(e, 2);  e += __shfl_xor(e, 1);
        if (lane == 0) out[s] = e + bo2[0];
    }
}

extern "C" void kernel_launch(void* const* d_in, const int* in_sizes, int n_in,
                              void* d_out, int out_size, void* d_ws, size_t ws_size,
                              hipStream_t stream) {
    (void)in_sizes; (void)n_in; (void)out_size; (void)ws_size;
    const float* feat = (const float*)d_in[0];
    const int*   seg  = (const int*)d_in[1];
    const float* W1a  = (const float*)d_in[2];
    const float* b1a  = (const float*)d_in[3];
    const float* W1b  = (const float*)d_in[4];
    const float* b1b  = (const float*)d_in[5];
    const float* W2   = (const float*)d_in[6];
    const float* b2   = (const float*)d_in[7];
    const float* W3   = (const float*)d_in[8];
    const float* b3   = (const float*)d_in[9];
    const float* W4   = (const float*)d_in[10];
    const float* b4   = (const float*)d_in[11];
    const float* W5   = (const float*)d_in[12];
    const float* b5   = (const float*)d_in[13];
    const float* Wo1  = (const float*)d_in[14];
    const float* bo1  = (const float*)d_in[15];
    const float* Wo2  = (const float*)d_in[16];
    const float* bo2  = (const float*)d_in[17];
    float* out = (float*)d_out;

    unsigned short* wt = (unsigned short*)d_ws;                       // 5*16384 bf16
    int* offs = (int*)((char*)d_ws + 5 * 16384 * sizeof(unsigned short));

    seg_offsets_kernel<<<(NSEG + 256) / 256, 256, 0, stream>>>(seg, offs);
    wconv_kernel<<<(5 * 16384) / 256, 256, 0, stream>>>(W1b, W2, W3, W4, W5, wt);

    hipFuncSetAttribute((const void*)fused_pflow,
                        hipFuncAttributeMaxDynamicSharedMemorySize, LDS_BYTES);
    fused_pflow<<<NSEG, BLK, LDS_BYTES, stream>>>(feat, offs, wt, W1a, b1a,
                                                  b1b, b2, b3, b4, b5,
                                                  Wo1, bo1, Wo2, bo2, out);
}

// Round 2
// 855.150 us; speedup vs baseline: 1.3161x; 1.3161x over previous
//
#include <hip/hip_runtime.h>
#include <stdint.h>

#define NSEG 2048
#define NTOT 1048576
#define CAP  624            // max nodes per segment held in LDS (multiple of 16)
#define BLK  512
#define H_BYTES (CAP * 256)                      // bf16 h[CAP][128]
// LDS: h | cs[2][128] | lbias[128] | wbuf[512]
#define CS_OFF    H_BYTES
#define LBIAS_OFF (H_BYTES + 1024)
#define WBUF_OFF  (H_BYTES + 1024 + 512)
#define LDS_BYTES (H_BYTES + 1024 + 512 + 2048)  // 163328 <= 163840

typedef __bf16 bf16x8 __attribute__((ext_vector_type(8)));
typedef __bf16 bf16x4 __attribute__((ext_vector_type(4)));
typedef float  f32x4  __attribute__((ext_vector_type(4)));

__device__ __forceinline__ float leaky(float v) { return fmaxf(v, 0.01f * v); }
// swizzled byte address into LDS h tile: row pitch 256B, XOR bits 4-6 by row&7
__device__ __forceinline__ uint32_t haddr(int row, int bytecol) {
    return ((uint32_t)row * 256u + (uint32_t)bytecol) ^ (((uint32_t)row & 7u) << 4);
}

// offs[t] = lower_bound(seg, t): segment t occupies [offs[t], offs[t+1])
__global__ void seg_offsets_kernel(const int* __restrict__ seg, int* __restrict__ offs) {
    int t = blockIdx.x * blockDim.x + threadIdx.x;
    if (t > NSEG) return;
    int lo = 0, hi = NTOT;
    while (lo < hi) { int mid = (lo + hi) >> 1; if (seg[mid] < t) lo = mid + 1; else hi = mid; }
    offs[t] = lo;
}

// Wt[m][n][k] = bf16(W_m[k][n])  (transposed so k is contiguous for fragment loads)
__global__ void wconv_kernel(const float* __restrict__ W1b, const float* __restrict__ W2,
                             const float* __restrict__ W3,  const float* __restrict__ W4,
                             const float* __restrict__ W5,  __bf16* __restrict__ wt) {
    int idx = blockIdx.x * blockDim.x + threadIdx.x;   // 0 .. 5*16384-1
    int m = idx >> 14, e = idx & 16383;
    int nn = e >> 7, kk = e & 127;
    const float* W = (m == 0) ? W1b : (m == 1) ? W2 : (m == 2) ? W3 : (m == 3) ? W4 : W5;
    wt[idx] = (__bf16)W[kk * 128 + nn];
}

extern __shared__ char smem[];

__global__ __launch_bounds__(BLK, 2) __attribute__((amdgpu_waves_per_eu(2, 2)))
void fused_pflow(
    const float* __restrict__ feat, const int* __restrict__ offs,
    const __bf16* __restrict__ wt5,
    const float* __restrict__ W1a, const float* __restrict__ b1a,
    const float* __restrict__ Wl0, const float* __restrict__ bl0,   // W1b,b1b
    const float* __restrict__ Wl1, const float* __restrict__ bl1,   // W2,b2
    const float* __restrict__ Wl2, const float* __restrict__ bl2,
    const float* __restrict__ Wl3, const float* __restrict__ bl3,
    const float* __restrict__ Wl4, const float* __restrict__ bl4,
    const float* __restrict__ Wo1, const float* __restrict__ bo1,
    const float* __restrict__ Wo2, const float* __restrict__ bo2,
    float* __restrict__ out)
{
    const int s    = blockIdx.x;
    const int tid  = threadIdx.x;
    const int lane = tid & 63;
    const int wave = tid >> 6;
    const int lm   = lane & 15;    // MFMA node lane / A-row lane
    const int lq   = lane >> 4;    // k-quad / C row-quad

    char*  sm    = smem;
    float* cs0   = (float*)(sm + CS_OFF);      // column-sum ping
    float* cs1   = cs0 + 128;                  // column-sum pong
    float* lbias = (float*)(sm + LBIAS_OFF);   // folded bias of current layer
    float* wbuf  = (float*)(sm + WBUF_OFF);    // layer-1a W+b, [ch][4]

    const int g0 = offs[s];
    int n = offs[s + 1] - g0;
    n = n < CAP ? n : CAP;

    // wbuf[ch*4+j] = {W1a[0][ch], W1a[1][ch], W1a[2][ch], b1a[ch]}
    for (int i = tid; i < 512; i += BLK) {
        int ch = i >> 2, j = i & 3;
        wbuf[i] = (j < 3) ? W1a[j * 128 + ch] : b1a[ch];
    }
    if (tid < 256) cs0[tid] = 0.f;             // zero both cs buffers (contiguous)
    __syncthreads();

    // ---- layer 1a: h = leaky(feat @ W1a + b1a), fp32 VALU (K=3) ----
    for (int i = tid; i < n; i += BLK) {
        float f0 = feat[(g0 + i) * 3 + 0];
        float f1 = feat[(g0 + i) * 3 + 1];
        float f2 = feat[(g0 + i) * 3 + 2];
        #pragma unroll
        for (int c0 = 0; c0 < 128; c0 += 8) {
            bf16x8 pk;
            #pragma unroll
            for (int j = 0; j < 8; ++j) {
                const f32x4 w = *(const f32x4*)&wbuf[(c0 + j) * 4];
                pk[j] = (__bf16)leaky(fmaf(f0, w[0], fmaf(f1, w[1], fmaf(f2, w[2], w[3]))));
            }
            *(bf16x8*)(sm + haddr(i, c0 * 2)) = pk;
        }
    }

    const int   ntiles = (n + 15) >> 4;
    const float inv_n  = 1.f / (float)(n > 1 ? n : 1);

    // ---- 5 GEMM layers: h = leaky(h @ W + b'), b' = b + mean_prev @ W ----
    for (int L = 0; L < 5; ++L) {
        __syncthreads();                       // h stable, prev-layer atomics done
        float* csCur  = (L & 1) ? cs1 : cs0;
        float* csPrev = (L & 1) ? cs0 : cs1;
        if (L == 0) {
            if (tid < 128) lbias[tid] = bl0[tid];
        } else {
            // fold residual mean into bias: lbias = b + inv_n * (csPrev @ W), f32
            const float* Wc = (L == 1) ? Wl1 : (L == 2) ? Wl2 : (L == 3) ? Wl3 : Wl4;
            const float* bc = (L == 1) ? bl1 : (L == 2) ? bl2 : (L == 3) ? bl3 : bl4;
            const int ch = tid >> 2, q = tid & 3;
            float sacc = 0.f;
            #pragma unroll 8
            for (int i = 0; i < 32; ++i) {
                const int k = q * 32 + i;
                sacc = fmaf(csPrev[k], Wc[k * 128 + ch], sacc);
            }
            sacc += __shfl_xor(sacc, 1);
            sacc += __shfl_xor(sacc, 2);
            if (q == 0) lbias[ch] = fmaf(inv_n, sacc, bc[ch]);
            if (tid < 128) csCur[tid] = 0.f;
        }
        __syncthreads();                       // lbias ready, csCur zeroed

        // A = W^T fragments, whole 128x128 W register-resident (128 VGPR)
        const __bf16* wt = wt5 + L * 16384;
        bf16x8 afrag[8][4];
        #pragma unroll
        for (int ct = 0; ct < 8; ++ct)
            #pragma unroll
            for (int ks = 0; ks < 4; ++ks)
                afrag[ct][ks] = *(const bf16x8*)(wt + (ct * 16 + lm) * 128 + ks * 32 + lq * 8);
        f32x4 lbreg[8];
        #pragma unroll
        for (int ct = 0; ct < 8; ++ct)
            lbreg[ct] = *(const f32x4*)&lbias[ct * 16 + lq * 4];

        float creg[8][4] = {};                 // column-sum partials
        for (int rt = wave; rt < ntiles; rt += 8) {
            const int node = rt * 16 + lm;
            bf16x8 bfrag[4];                   // B = h^T: this lane's node, 4 k-groups
            #pragma unroll
            for (int ks = 0; ks < 4; ++ks)
                bfrag[ks] = *(const bf16x8*)(sm + haddr(node, ks * 64 + lq * 16));
            f32x4 acc[8];
            #pragma unroll
            for (int ct = 0; ct < 8; ++ct) acc[ct] = lbreg[ct];   // bias in C-operand
            #pragma unroll
            for (int ks = 0; ks < 4; ++ks)
                #pragma unroll
                for (int ct = 0; ct < 8; ++ct)
                    acc[ct] = __builtin_amdgcn_mfma_f32_16x16x32_bf16(afrag[ct][ks], bfrag[ks], acc[ct], 0, 0, 0);
            if (node < n) {
                #pragma unroll
                for (int ct = 0; ct < 8; ++ct) {
                    bf16x4 pk;
                    #pragma unroll
                    for (int i = 0; i < 4; ++i) {
                        float v = leaky(acc[ct][i]);
                        creg[ct][i] += v;
                        pk[i] = (__bf16)v;     // compiler emits v_cvt_pk_bf16_f32
                    }
                    *(bf16x4*)(sm + haddr(node, (ct * 16 + lq * 4) * 2)) = pk;
                }
            }
        }
        // reduce column-sum partials over the 16 node-lanes, one atomic per channel
        #pragma unroll
        for (int ct = 0; ct < 8; ++ct)
            #pragma unroll
            for (int i = 0; i < 4; ++i) {
                float v = creg[ct][i];
                v += __shfl_xor(v, 1); v += __shfl_xor(v, 2);
                v += __shfl_xor(v, 4); v += __shfl_xor(v, 8);
                if (lm == 0) atomicAdd(&csCur[ct * 16 + lq * 4 + i], v);
            }
    }
    __syncthreads();                           // layer-5 atomics into cs0 done

    // ---- output head: g = cs0*inv_n; e = leaky(g@Wo1+bo1)@Wo2 + bo2 ----
    if (wave == 0) {
        float a = bo1[lane];                   // 64 lanes = 64 hidden units
        for (int k = 0; k < 128; ++k)
            a = fmaf(cs0[k] * inv_n, Wo1[k * 64 + lane], a);
        a = leaky(a);
        float e = a * Wo2[lane];
        e += __shfl_xor(e, 32); e += __shfl_xor(e, 16); e += __shfl_xor(e, 8);
        e += __shfl_xor(e, 4);  e += __shfl_xor(e, 2);  e += __shfl_xor(e, 1);
        if (lane == 0) out[s] = e + bo2[0];
    }
}

extern "C" void kernel_launch(void* const* d_in, const int* in_sizes, int n_in,
                              void* d_out, int out_size, void* d_ws, size_t ws_size,
                              hipStream_t stream) {
    (void)in_sizes; (void)n_in; (void)out_size; (void)ws_size;
    const float* feat = (const float*)d_in[0];
    const int*   seg  = (const int*)d_in[1];
    const float* W1a  = (const float*)d_in[2];
    const float* b1a  = (const float*)d_in[3];
    const float* W1b  = (const float*)d_in[4];
    const float* b1b  = (const float*)d_in[5];
    const float* W2   = (const float*)d_in[6];
    const float* b2   = (const float*)d_in[7];
    const float* W3   = (const float*)d_in[8];
    const float* b3   = (const float*)d_in[9];
    const float* W4   = (const float*)d_in[10];
    const float* b4   = (const float*)d_in[11];
    const float* W5   = (const float*)d_in[12];
    const float* b5   = (const float*)d_in[13];
    const float* Wo1  = (const float*)d_in[14];
    const float* bo1  = (const float*)d_in[15];
    const float* Wo2  = (const float*)d_in[16];
    const float* bo2  = (const float*)d_in[17];
    float* out = (float*)d_out;

    __bf16* wt = (__bf16*)d_ws;                                   // 5*16384 bf16
    int* offs = (int*)((char*)d_ws + 5 * 16384 * sizeof(__bf16));

    seg_offsets_kernel<<<(NSEG + 256) / 256, 256, 0, stream>>>(seg, offs);
    wconv_kernel<<<(5 * 16384) / 256, 256, 0, stream>>>(W1b, W2, W3, W4, W5, wt);

    hipFuncSetAttribute((const void*)fused_pflow,
                        hipFuncAttributeMaxDynamicSharedMemorySize, LDS_BYTES);
    fused_pflow<<<NSEG, BLK, LDS_BYTES, stream>>>(feat, offs, wt, W1a, b1a,
                                                  W1b, b1b, W2, b2, W3, b3,
                                                  W4, b4, W5, b5,
                                                  Wo1, bo1, Wo2, bo2, out);
}

// Round 3
// 831.178 us; speedup vs baseline: 1.3540x; 1.0288x over previous
//
#include <hip/hip_runtime.h>
#include <stdint.h>

#define NSEG 2048
#define NTOT 1048576
#define CAP  624            // max nodes per segment held in LDS (multiple of 16)
#define BLK  512
#define H_BYTES (CAP * 256)                      // bf16 h[CAP][128]
// LDS: h | cs[2][128] | lbias[128] | wbuf[512]
#define CS_OFF    H_BYTES
#define LBIAS_OFF (H_BYTES + 1024)
#define WBUF_OFF  (H_BYTES + 1024 + 512)
#define LDS_BYTES (H_BYTES + 1024 + 512 + 2048)  // 163328 <= 163840

typedef __bf16 bf16x8 __attribute__((ext_vector_type(8)));
typedef __bf16 bf16x4 __attribute__((ext_vector_type(4)));
typedef float  f32x4  __attribute__((ext_vector_type(4)));

__device__ __forceinline__ float leaky(float v) { return fmaxf(v, 0.01f * v); }
// swizzled byte address into LDS h tile: row pitch 256B, XOR bits 4-6 by row&7
__device__ __forceinline__ uint32_t haddr(int row, int bytecol) {
    return ((uint32_t)row * 256u + (uint32_t)bytecol) ^ (((uint32_t)row & 7u) << 4);
}

// offs[t] = lower_bound(seg, t): segment t occupies [offs[t], offs[t+1])
__global__ void seg_offsets_kernel(const int* __restrict__ seg, int* __restrict__ offs) {
    int t = blockIdx.x * blockDim.x + threadIdx.x;
    if (t > NSEG) return;
    int lo = 0, hi = NTOT;
    while (lo < hi) { int mid = (lo + hi) >> 1; if (seg[mid] < t) lo = mid + 1; else hi = mid; }
    offs[t] = lo;
}

// Wt[m][n][k] = bf16(W_m[k][n])  (transposed so k is contiguous for fragment loads)
__global__ void wconv_kernel(const float* __restrict__ W1b, const float* __restrict__ W2,
                             const float* __restrict__ W3,  const float* __restrict__ W4,
                             const float* __restrict__ W5,  __bf16* __restrict__ wt) {
    int idx = blockIdx.x * blockDim.x + threadIdx.x;   // 0 .. 5*16384-1
    int m = idx >> 14, e = idx & 16383;
    int nn = e >> 7, kk = e & 127;
    const float* W = (m == 0) ? W1b : (m == 1) ? W2 : (m == 2) ? W3 : (m == 3) ? W4 : W5;
    wt[idx] = (__bf16)W[kk * 128 + nn];
}

extern __shared__ char smem[];

__global__ void __attribute__((amdgpu_flat_work_group_size(512, 512),
                               amdgpu_waves_per_eu(2, 2)))
fused_pflow(
    const float* __restrict__ feat, const int* __restrict__ offs,
    const __bf16* __restrict__ wt5,
    const float* __restrict__ W1a, const float* __restrict__ b1a,
    const float* __restrict__ Wl0, const float* __restrict__ bl0,   // W1b,b1b
    const float* __restrict__ Wl1, const float* __restrict__ bl1,   // W2,b2
    const float* __restrict__ Wl2, const float* __restrict__ bl2,
    const float* __restrict__ Wl3, const float* __restrict__ bl3,
    const float* __restrict__ Wl4, const float* __restrict__ bl4,
    const float* __restrict__ Wo1, const float* __restrict__ bo1,
    const float* __restrict__ Wo2, const float* __restrict__ bo2,
    float* __restrict__ out)
{
    const int s    = blockIdx.x;
    const int tid  = threadIdx.x;
    const int lane = tid & 63;
    const int wave = tid >> 6;
    const int lm   = lane & 15;    // MFMA node lane / A-row lane
    const int lq   = lane >> 4;    // k-quad / C row-quad

    char*  sm    = smem;
    float* cs0   = (float*)(sm + CS_OFF);      // column-sum ping
    float* cs1   = cs0 + 128;                  // column-sum pong
    float* lbias = (float*)(sm + LBIAS_OFF);   // folded bias of current layer
    float* wbuf  = (float*)(sm + WBUF_OFF);    // layer-1a W+b, [ch][4]

    const int g0 = offs[s];
    int n = offs[s + 1] - g0;
    n = n < CAP ? n : CAP;

    // wbuf[ch*4+j] = {W1a[0][ch], W1a[1][ch], W1a[2][ch], b1a[ch]}
    for (int i = tid; i < 512; i += BLK) {
        int ch = i >> 2, j = i & 3;
        wbuf[i] = (j < 3) ? W1a[j * 128 + ch] : b1a[ch];
    }
    if (tid < 256) cs0[tid] = 0.f;             // zero both cs buffers (contiguous)
    __syncthreads();

    // ---- layer 1a: h = leaky(feat @ W1a + b1a), fp32 VALU (K=3) ----
    for (int i = tid; i < n; i += BLK) {
        float f0 = feat[(g0 + i) * 3 + 0];
        float f1 = feat[(g0 + i) * 3 + 1];
        float f2 = feat[(g0 + i) * 3 + 2];
        #pragma unroll
        for (int c0 = 0; c0 < 128; c0 += 8) {
            bf16x8 pk;
            #pragma unroll
            for (int j = 0; j < 8; ++j) {
                const f32x4 w = *(const f32x4*)&wbuf[(c0 + j) * 4];
                pk[j] = (__bf16)leaky(fmaf(f0, w[0], fmaf(f1, w[1], fmaf(f2, w[2], w[3]))));
            }
            *(bf16x8*)(sm + haddr(i, c0 * 2)) = pk;
        }
    }

    const int   ntiles = (n + 15) >> 4;
    const float inv_n  = 1.f / (float)(n > 1 ? n : 1);

    // ---- 5 GEMM layers: h = leaky(h @ W + b'), b' = b + mean_prev @ W ----
    for (int L = 0; L < 5; ++L) {
        __syncthreads();                       // h stable, prev-layer atomics done
        float* csCur  = (L & 1) ? cs1 : cs0;
        float* csPrev = (L & 1) ? cs0 : cs1;
        if (L == 0) {
            if (tid < 128) lbias[tid] = bl0[tid];
        } else {
            // fold residual mean into bias: lbias = b + inv_n * (csPrev @ W), f32
            const float* Wc = (L == 1) ? Wl1 : (L == 2) ? Wl2 : (L == 3) ? Wl3 : Wl4;
            const float* bc = (L == 1) ? bl1 : (L == 2) ? bl2 : (L == 3) ? bl3 : bl4;
            const int ch = tid >> 2, q = tid & 3;
            float sacc = 0.f;
            #pragma unroll 8
            for (int i = 0; i < 32; ++i) {
                const int k = q * 32 + i;
                sacc = fmaf(csPrev[k], Wc[k * 128 + ch], sacc);
            }
            sacc += __shfl_xor(sacc, 1);
            sacc += __shfl_xor(sacc, 2);
            if (q == 0) lbias[ch] = fmaf(inv_n, sacc, bc[ch]);
            if (tid < 128) csCur[tid] = 0.f;
        }
        __syncthreads();                       // lbias ready, csCur zeroed

        // A = W^T fragments, whole 128x128 W register-resident (128 VGPR)
        const __bf16* wt = wt5 + L * 16384;
        bf16x8 afrag[8][4];
        #pragma unroll
        for (int ct = 0; ct < 8; ++ct)
            #pragma unroll
            for (int ks = 0; ks < 4; ++ks)
                afrag[ct][ks] = *(const bf16x8*)(wt + (ct * 16 + lm) * 128 + ks * 32 + lq * 8);

        float creg[8][4] = {};                 // column-sum partials
        for (int rt = wave; rt < ntiles; rt += 8) {
            const int node = rt * 16 + lm;
            bf16x8 bfrag[4];                   // B = h^T: this lane's node, 4 k-groups
            #pragma unroll
            for (int ks = 0; ks < 4; ++ks)
                bfrag[ks] = *(const bf16x8*)(sm + haddr(node, ks * 64 + lq * 16));
            f32x4 acc[8];
            #pragma unroll
            for (int ct = 0; ct < 8; ++ct)     // bias in C-operand via LDS read
                acc[ct] = *(const f32x4*)&lbias[ct * 16 + lq * 4];
            #pragma unroll
            for (int ks = 0; ks < 4; ++ks)
                #pragma unroll
                for (int ct = 0; ct < 8; ++ct)
                    acc[ct] = __builtin_amdgcn_mfma_f32_16x16x32_bf16(afrag[ct][ks], bfrag[ks], acc[ct], 0, 0, 0);
            if (node < n) {
                #pragma unroll
                for (int ct = 0; ct < 8; ++ct) {
                    bf16x4 pk;
                    #pragma unroll
                    for (int i = 0; i < 4; ++i) {
                        float v = leaky(acc[ct][i]);
                        creg[ct][i] += v;
                        pk[i] = (__bf16)v;     // compiler emits v_cvt_pk_bf16_f32
                    }
                    *(bf16x4*)(sm + haddr(node, (ct * 16 + lq * 4) * 2)) = pk;
                }
            }
        }
        // reduce column-sum partials over the 16 node-lanes, one atomic per channel
        #pragma unroll
        for (int ct = 0; ct < 8; ++ct)
            #pragma unroll
            for (int i = 0; i < 4; ++i) {
                float v = creg[ct][i];
                v += __shfl_xor(v, 1); v += __shfl_xor(v, 2);
                v += __shfl_xor(v, 4); v += __shfl_xor(v, 8);
                if (lm == 0) atomicAdd(&csCur[ct * 16 + lq * 4 + i], v);
            }
    }
    __syncthreads();                           // layer-5 atomics into cs0 done

    // ---- output head: g = cs0*inv_n; e = leaky(g@Wo1+bo1)@Wo2 + bo2 ----
    if (wave == 0) {
        float a = bo1[lane];                   // 64 lanes = 64 hidden units
        for (int k = 0; k < 128; ++k)
            a = fmaf(cs0[k] * inv_n, Wo1[k * 64 + lane], a);
        a = leaky(a);
        float e = a * Wo2[lane];
        e += __shfl_xor(e, 32); e += __shfl_xor(e, 16); e += __shfl_xor(e, 8);
        e += __shfl_xor(e, 4);  e += __shfl_xor(e, 2);  e += __shfl_xor(e, 1);
        if (lane == 0) out[s] = e + bo2[0];
    }
}

extern "C" void kernel_launch(void* const* d_in, const int* in_sizes, int n_in,
                              void* d_out, int out_size, void* d_ws, size_t ws_size,
                              hipStream_t stream) {
    (void)in_sizes; (void)n_in; (void)out_size; (void)ws_size;
    const float* feat = (const float*)d_in[0];
    const int*   seg  = (const int*)d_in[1];
    const float* W1a  = (const float*)d_in[2];
    const float* b1a  = (const float*)d_in[3];
    const float* W1b  = (const float*)d_in[4];
    const float* b1b  = (const float*)d_in[5];
    const float* W2   = (const float*)d_in[6];
    const float* b2   = (const float*)d_in[7];
    const float* W3   = (const float*)d_in[8];
    const float* b3   = (const float*)d_in[9];
    const float* W4   = (const float*)d_in[10];
    const float* b4   = (const float*)d_in[11];
    const float* W5   = (const float*)d_in[12];
    const float* b5   = (const float*)d_in[13];
    const float* Wo1  = (const float*)d_in[14];
    const float* bo1  = (const float*)d_in[15];
    const float* Wo2  = (const float*)d_in[16];
    const float* bo2  = (const float*)d_in[17];
    float* out = (float*)d_out;

    __bf16* wt = (__bf16*)d_ws;                                   // 5*16384 bf16
    int* offs = (int*)((char*)d_ws + 5 * 16384 * sizeof(__bf16));

    seg_offsets_kernel<<<(NSEG + 256) / 256, 256, 0, stream>>>(seg, offs);
    wconv_kernel<<<(5 * 16384) / 256, 256, 0, stream>>>(W1b, W2, W3, W4, W5, wt);

    hipFuncSetAttribute((const void*)fused_pflow,
                        hipFuncAttributeMaxDynamicSharedMemorySize, LDS_BYTES);
    fused_pflow<<<NSEG, BLK, LDS_BYTES, stream>>>(feat, offs, wt, W1a, b1a,
                                                  W1b, b1b, W2, b2, W3, b3,
                                                  W4, b4, W5, b5,
                                                  Wo1, bo1, Wo2, bo2, out);
}